// Round 3
// baseline (936.261 us; speedup 1.0000x reference)
//
#include <hip/hip_runtime.h>

// ============================================================================
// Fully-fused 3-layer Elman RNN, *** FP32 in/out ***, MFMA 16x16x32 bf16 via
// Ootomo 3-term double-bf16 products (ah*bh + ah*bl + al*bh, err ~2^-18).
//   B=8192, T=64, dims: 84 -> 128 -> 128 -> 84
// R3 change: rounds 1-2 read the fp32 input buffers as bf16 (absmax stuck at
// max|ref|+1.0 = saturated garbage, bit-identical across precision changes ->
// structural dtype bug, not numerics). Reference dtype is float32; harness
// threshold = 2% * max|ref| (dtype-agnostic).
//   - Weights: hi/lo bf16 register frags (88 frags = 352 VGPRs, 1 wave/SIMD).
//   - x: per-timestep hi/lo LDS staging, ping-ponged in the L1 phase.
//   - h: hi/lo LDS planes, double-buffered (as R2).
//   - 2 __syncthreads per timestep (hazard-audited incl. xbuf ping-pong).
// ============================================================================

typedef __bf16 bf16x8 __attribute__((ext_vector_type(8)));
typedef float  f32x4  __attribute__((ext_vector_type(4)));
typedef unsigned short u16;
typedef unsigned int   u32;
typedef u16 u16x8 __attribute__((ext_vector_type(8)));

#define MFMA16(a, b, c) __builtin_amdgcn_mfma_f32_16x16x32_bf16((a), (b), (c), 0, 0, 0)

__device__ __forceinline__ float bf2f(u16 v) {
    return __builtin_bit_cast(float, (u32)v << 16);
}
// float -> bf16 round-to-nearest-even (finite inputs only)
__device__ __forceinline__ u16 f2bf(float f) {
    u32 u = __builtin_bit_cast(u32, f);
    u = u + 0x7fffu + ((u >> 16) & 1u);
    return (u16)(u >> 16);
}
__device__ __forceinline__ float tanh_fast(float x) {
    float xc = fminf(fmaxf(x, -12.f), 12.f);           // avoid inf/inf
    float e  = __expf(2.f * xc);
    return (e - 1.f) * __builtin_amdgcn_rcpf(e + 1.f); // ~1e-7 rel err
}
__device__ __forceinline__ f32x4 splat4(float v) {
    f32x4 r; r[0] = v; r[1] = v; r[2] = v; r[3] = v; return r;
}
__device__ __forceinline__ bf16x8 ld_lds8(const u16* p) {
    return __builtin_bit_cast(bf16x8, *(const u16x8*)p);
}
// split fp32 into hi+lo bf16 (v - hi exact in fp32; residual ~2^-18 * |v|)
__device__ __forceinline__ void store_hl(u16* ph, u16* pl, float v) {
    u16 hi = f2bf(v);
    *ph = hi;
    *pl = f2bf(v - bf2f(hi));
}

struct fragp { bf16x8 h, l; };   // hi/lo weight fragment pair

// B-frag pair for C = A @ W^T, W fp32 row-major [Hr][Kr]; lane col n holds
// W[n][kbase..kbase+8) split hi/lo. Zero-pads OOB rows/cols.
__device__ __forceinline__ fragp load_wfrag_hl(const float* W, int Hr, int Kr,
                                               int n, int kbase) {
    u16x8 uh = {0,0,0,0,0,0,0,0}, ul = {0,0,0,0,0,0,0,0};
    if (n < Hr) {
#pragma unroll
        for (int j = 0; j < 8; j++) {
            int k = kbase + j;
            if (k < Kr) {
                float w = W[n * Kr + k];
                u16 hi = f2bf(w);
                uh[j] = hi;
                ul[j] = f2bf(w - bf2f(hi));
            }
        }
    }
    fragp r;
    r.h = __builtin_bit_cast(bf16x8, uh);
    r.l = __builtin_bit_cast(bf16x8, ul);
    return r;
}

// 3-term double-bf16 product accumulate: c += (ah+al) * (bh+bl) - O(2^-18)
__device__ __forceinline__ f32x4 mm3(bf16x8 ah, bf16x8 al, const fragp& b, f32x4 c) {
    c = MFMA16(ah, b.h, c);
    c = MFMA16(ah, b.l, c);
    c = MFMA16(al, b.h, c);
    return c;
}

__global__ __launch_bounds__(256, 1)  // 1 wave/SIMD: up to 512 VGPRs for 88 weight frags
void rnn_fused(const float* __restrict__ x,
               const float* __restrict__ wih0, const float* __restrict__ whh0,
               const float* __restrict__ bih0, const float* __restrict__ bhh0,
               const float* __restrict__ wih1, const float* __restrict__ whh1,
               const float* __restrict__ bih1, const float* __restrict__ bhh1,
               const float* __restrict__ wih2, const float* __restrict__ whh2,
               const float* __restrict__ bih2, const float* __restrict__ bhh2,
               float* __restrict__ out)
{
    // hi/lo planes, double-buffered by t parity. Row strides 136/104/96 els:
    // 16B-aligned rows for ds_read_b128; 2-way bank alias is free (m136).
    __shared__ __align__(16) u16 h0h[2][32][136], h0l[2][32][136];
    __shared__ __align__(16) u16 h1h[2][32][136], h1l[2][32][136];
    __shared__ __align__(16) u16 h2h[2][32][104], h2l[2][32][104];
    __shared__ __align__(16) u16 xbh[2][32][96],  xbl[2][32][96];   // x_t staging

    const int tid  = threadIdx.x;
    const int wv   = tid >> 6;        // wave 0..3
    const int lane = tid & 63;
    const int ln   = lane & 15;       // A-row / C-col index
    const int q    = lane >> 4;       // quad
    const int b0   = blockIdx.x * 32;
    const float* xg = x + (long)b0 * 5376;   // this block's 32 batch rows

    // h_{-1} = 0 (parity-0 planes)
    { u16* z = &h0h[0][0][0]; for (int i = tid; i < 32 * 136; i += 256) z[i] = 0; }
    { u16* z = &h0l[0][0][0]; for (int i = tid; i < 32 * 136; i += 256) z[i] = 0; }
    { u16* z = &h1h[0][0][0]; for (int i = tid; i < 32 * 136; i += 256) z[i] = 0; }
    { u16* z = &h1l[0][0][0]; for (int i = tid; i < 32 * 136; i += 256) z[i] = 0; }
    { u16* z = &h2h[0][0][0]; for (int i = tid; i < 32 * 104; i += 256) z[i] = 0; }
    { u16* z = &h2l[0][0][0]; for (int i = tid; i < 32 * 104; i += 256) z[i] = 0; }
    // x pad cols 84..95, both parities, both planes (written once)
    for (int i = tid; i < 32 * 12 * 2; i += 256) {
        int par = i / (32 * 12), rem = i - par * 32 * 12;
        int row = rem / 12, col = 84 + rem - row * 12;
        xbh[par][row][col] = 0; xbl[par][row][col] = 0;
    }
    // stage x_0 into parity 0
    for (int i = tid; i < 32 * 84; i += 256) {
        int row = i / 84, col = i - row * 84;
        float v = xg[(long)row * 5376 + col];
        u16 hi = f2bf(v);
        xbh[0][row][col] = hi;
        xbl[0][row][col] = f2bf(v - bf2f(hi));
    }

    // wave wv owns output N-tiles {wv, wv+4}
    const int n0 = wv * 16 + ln;
    const int n1 = (wv + 4) * 16 + ln;

    // ---- register-resident hi/lo weight B-frags (88 frags = 352 VGPRs) ----
    fragp fih0[2][3], fhh0[2][4], fih1[2][4], fhh1[2][4], fih2[2][4], fhh2[2][3];
#pragma unroll
    for (int c = 0; c < 3; c++) {
        fih0[0][c] = load_wfrag_hl(wih0, 128, 84, n0, c * 32 + q * 8);
        fih0[1][c] = load_wfrag_hl(wih0, 128, 84, n1, c * 32 + q * 8);
        fhh2[0][c] = load_wfrag_hl(whh2, 84, 84, n0, c * 32 + q * 8);
        fhh2[1][c] = load_wfrag_hl(whh2, 84, 84, n1, c * 32 + q * 8);  // n1>=96 -> zeros
    }
#pragma unroll
    for (int c = 0; c < 4; c++) {
        fhh0[0][c] = load_wfrag_hl(whh0, 128, 128, n0, c * 32 + q * 8);
        fhh0[1][c] = load_wfrag_hl(whh0, 128, 128, n1, c * 32 + q * 8);
        fih1[0][c] = load_wfrag_hl(wih1, 128, 128, n0, c * 32 + q * 8);
        fih1[1][c] = load_wfrag_hl(wih1, 128, 128, n1, c * 32 + q * 8);
        fhh1[0][c] = load_wfrag_hl(whh1, 128, 128, n0, c * 32 + q * 8);
        fhh1[1][c] = load_wfrag_hl(whh1, 128, 128, n1, c * 32 + q * 8);
        fih2[0][c] = load_wfrag_hl(wih2, 84, 128, n0, c * 32 + q * 8);
        fih2[1][c] = load_wfrag_hl(wih2, 84, 128, n1, c * 32 + q * 8);
    }
    const float bias0[2] = { (n0 < 128) ? bih0[n0] + bhh0[n0] : 0.f,
                             (n1 < 128) ? bih0[n1] + bhh0[n1] : 0.f };
    const float bias1[2] = { (n0 < 128) ? bih1[n0] + bhh1[n0] : 0.f,
                             (n1 < 128) ? bih1[n1] + bhh1[n1] : 0.f };
    const float bias2[2] = { (n0 <  84) ? bih2[n0] + bhh2[n0] : 0.f,
                             (n1 <  84) ? bih2[n1] + bhh2[n1] : 0.f };

    __syncthreads();

    f32x4 acc[2][2];  // [m-tile][n-tile]

    for (int t = 0; t < 64; ++t) {
        const int p = t & 1, pn = p ^ 1;

        // ================= layer 0 : 84 -> 128 =================
#pragma unroll
        for (int mt = 0; mt < 2; mt++) { acc[mt][0] = splat4(bias0[0]); acc[mt][1] = splat4(bias0[1]); }
#pragma unroll
        for (int c = 0; c < 3; c++) {            // x-projection from staged x_t
            const int off = c * 32 + q * 8;
            bf16x8 a0h = ld_lds8(&xbh[p][ln][off]),      a0l = ld_lds8(&xbl[p][ln][off]);
            bf16x8 a1h = ld_lds8(&xbh[p][16 + ln][off]), a1l = ld_lds8(&xbl[p][16 + ln][off]);
            acc[0][0] = mm3(a0h, a0l, fih0[0][c], acc[0][0]);
            acc[0][1] = mm3(a0h, a0l, fih0[1][c], acc[0][1]);
            acc[1][0] = mm3(a1h, a1l, fih0[0][c], acc[1][0]);
            acc[1][1] = mm3(a1h, a1l, fih0[1][c], acc[1][1]);
        }
#pragma unroll
        for (int c = 0; c < 4; c++) {            // recurrence
            const int off = c * 32 + q * 8;
            bf16x8 a0h = ld_lds8(&h0h[p][ln][off]),      a0l = ld_lds8(&h0l[p][ln][off]);
            bf16x8 a1h = ld_lds8(&h0h[p][16 + ln][off]), a1l = ld_lds8(&h0l[p][16 + ln][off]);
            acc[0][0] = mm3(a0h, a0l, fhh0[0][c], acc[0][0]);
            acc[0][1] = mm3(a0h, a0l, fhh0[1][c], acc[0][1]);
            acc[1][0] = mm3(a1h, a1l, fhh0[0][c], acc[1][0]);
            acc[1][1] = mm3(a1h, a1l, fhh0[1][c], acc[1][1]);
        }
#pragma unroll
        for (int r = 0; r < 4; r++) {            // C/D: row = q*4+r, col = n0/n1
            const int row = q * 4 + r;
            store_hl(&h0h[pn][row     ][n0], &h0l[pn][row     ][n0], tanh_fast(acc[0][0][r]));
            store_hl(&h0h[pn][row     ][n1], &h0l[pn][row     ][n1], tanh_fast(acc[0][1][r]));
            store_hl(&h0h[pn][16 + row][n0], &h0l[pn][16 + row][n0], tanh_fast(acc[1][0][r]));
            store_hl(&h0h[pn][16 + row][n1], &h0l[pn][16 + row][n1], tanh_fast(acc[1][1][r]));
        }
        __syncthreads();   // barrier 1: h0_t ready for L1

        // stage x_{t+1} into xbuf[pn] (read by L0 of t+1, after barrier 2 -> safe)
        if (t < 63) {
            for (int i = tid; i < 32 * 84; i += 256) {
                int row = i / 84, col = i - row * 84;
                float v = xg[(long)row * 5376 + (t + 1) * 84 + col];
                u16 hi = f2bf(v);
                xbh[pn][row][col] = hi;
                xbl[pn][row][col] = f2bf(v - bf2f(hi));
            }
        }

        // ================= layer 1 : 128 -> 128 =================
#pragma unroll
        for (int mt = 0; mt < 2; mt++) { acc[mt][0] = splat4(bias1[0]); acc[mt][1] = splat4(bias1[1]); }
#pragma unroll
        for (int c = 0; c < 4; c++) {            // input proj from h0_t
            const int off = c * 32 + q * 8;
            bf16x8 a0h = ld_lds8(&h0h[pn][ln][off]),      a0l = ld_lds8(&h0l[pn][ln][off]);
            bf16x8 a1h = ld_lds8(&h0h[pn][16 + ln][off]), a1l = ld_lds8(&h0l[pn][16 + ln][off]);
            acc[0][0] = mm3(a0h, a0l, fih1[0][c], acc[0][0]);
            acc[0][1] = mm3(a0h, a0l, fih1[1][c], acc[0][1]);
            acc[1][0] = mm3(a1h, a1l, fih1[0][c], acc[1][0]);
            acc[1][1] = mm3(a1h, a1l, fih1[1][c], acc[1][1]);
        }
#pragma unroll
        for (int c = 0; c < 4; c++) {            // recurrence
            const int off = c * 32 + q * 8;
            bf16x8 a0h = ld_lds8(&h1h[p][ln][off]),      a0l = ld_lds8(&h1l[p][ln][off]);
            bf16x8 a1h = ld_lds8(&h1h[p][16 + ln][off]), a1l = ld_lds8(&h1l[p][16 + ln][off]);
            acc[0][0] = mm3(a0h, a0l, fhh1[0][c], acc[0][0]);
            acc[0][1] = mm3(a0h, a0l, fhh1[1][c], acc[0][1]);
            acc[1][0] = mm3(a1h, a1l, fhh1[0][c], acc[1][0]);
            acc[1][1] = mm3(a1h, a1l, fhh1[1][c], acc[1][1]);
        }
#pragma unroll
        for (int r = 0; r < 4; r++) {
            const int row = q * 4 + r;
            store_hl(&h1h[pn][row     ][n0], &h1l[pn][row     ][n0], tanh_fast(acc[0][0][r]));
            store_hl(&h1h[pn][row     ][n1], &h1l[pn][row     ][n1], tanh_fast(acc[0][1][r]));
            store_hl(&h1h[pn][16 + row][n0], &h1l[pn][16 + row][n0], tanh_fast(acc[1][0][r]));
            store_hl(&h1h[pn][16 + row][n1], &h1l[pn][16 + row][n1], tanh_fast(acc[1][1][r]));
        }
        __syncthreads();   // barrier 2: h1_t (and x_{t+1}) ready

        // ================= layer 2 : 128 -> 84 =================
#pragma unroll
        for (int mt = 0; mt < 2; mt++) { acc[mt][0] = splat4(bias2[0]); acc[mt][1] = splat4(bias2[1]); }
#pragma unroll
        for (int c = 0; c < 4; c++) {            // input proj from h1_t
            const int off = c * 32 + q * 8;
            bf16x8 a0h = ld_lds8(&h1h[pn][ln][off]),      a0l = ld_lds8(&h1l[pn][ln][off]);
            bf16x8 a1h = ld_lds8(&h1h[pn][16 + ln][off]), a1l = ld_lds8(&h1l[pn][16 + ln][off]);
            acc[0][0] = mm3(a0h, a0l, fih2[0][c], acc[0][0]);
            acc[0][1] = mm3(a0h, a0l, fih2[1][c], acc[0][1]);
            acc[1][0] = mm3(a1h, a1l, fih2[0][c], acc[1][0]);
            acc[1][1] = mm3(a1h, a1l, fih2[1][c], acc[1][1]);
        }
#pragma unroll
        for (int c = 0; c < 3; c++) {            // recurrence (K=96, 84 zero-padded)
            const int off = c * 32 + q * 8;
            bf16x8 a0h = ld_lds8(&h2h[p][ln][off]),      a0l = ld_lds8(&h2l[p][ln][off]);
            bf16x8 a1h = ld_lds8(&h2h[p][16 + ln][off]), a1l = ld_lds8(&h2l[p][16 + ln][off]);
            acc[0][0] = mm3(a0h, a0l, fhh2[0][c], acc[0][0]);
            acc[0][1] = mm3(a0h, a0l, fhh2[1][c], acc[0][1]);
            acc[1][0] = mm3(a1h, a1l, fhh2[0][c], acc[1][0]);
            acc[1][1] = mm3(a1h, a1l, fhh2[1][c], acc[1][1]);
        }
        // epilogue: pad cols (84..95) compute to exactly 0 (zeroed W frags+bias)
#pragma unroll
        for (int r = 0; r < 4; r++) {
            const int row = q * 4 + r;
            float v00 = tanh_fast(acc[0][0][r]);
            float v01 = tanh_fast(acc[0][1][r]);
            float v10 = tanh_fast(acc[1][0][r]);
            float v11 = tanh_fast(acc[1][1][r]);
            store_hl(&h2h[pn][row     ][n0], &h2l[pn][row     ][n0], v00);
            store_hl(&h2h[pn][16 + row][n0], &h2l[pn][16 + row][n0], v10);
            if (n1 < 96) {                        // waves 2,3: n1-tile is padding-only
                store_hl(&h2h[pn][row     ][n1], &h2l[pn][row     ][n1], v01);
                store_hl(&h2h[pn][16 + row][n1], &h2l[pn][16 + row][n1], v11);
            }
            float* o0 = out + (long)(b0 + row)      * 5376 + t * 84;
            float* o1 = out + (long)(b0 + 16 + row) * 5376 + t * 84;
            o0[n0] = v00;
            o1[n0] = v10;
            if (n1 < 84) { o0[n1] = v01; o1[n1] = v11; }
        }
        // no barrier here: next-step L0 reads h0[pn]/xbuf[pn] only; all remaining
        // ping-pong hazards are separated by the two barriers of the next
        // iteration (audited R1-R3, incl. xbuf: write in L1(t) between b1/b2,
        // read in L0(t+1) after b2(t), rewritten earliest in L1(t+2)).
    }
}

extern "C" void kernel_launch(void* const* d_in, const int* in_sizes, int n_in,
                              void* d_out, int out_size, void* d_ws, size_t ws_size,
                              hipStream_t stream) {
    (void)in_sizes; (void)n_in; (void)out_size; (void)d_ws; (void)ws_size;
    const float* x    = (const float*)d_in[0];
    const float* wih0 = (const float*)d_in[1];
    const float* whh0 = (const float*)d_in[2];
    const float* bih0 = (const float*)d_in[3];
    const float* bhh0 = (const float*)d_in[4];
    const float* wih1 = (const float*)d_in[5];
    const float* whh1 = (const float*)d_in[6];
    const float* bih1 = (const float*)d_in[7];
    const float* bhh1 = (const float*)d_in[8];
    const float* wih2 = (const float*)d_in[9];
    const float* whh2 = (const float*)d_in[10];
    const float* bih2 = (const float*)d_in[11];
    const float* bhh2 = (const float*)d_in[12];
    float* out = (float*)d_out;

    rnn_fused<<<dim3(8192 / 32), dim3(256), 0, stream>>>(
        x, wih0, whh0, bih0, bhh0, wih1, whh1, bih1, bhh1,
        wih2, whh2, bih2, bhh2, out);
}